// Round 5
// baseline (3098.492 us; speedup 1.0000x reference)
//
#include <hip/hip_runtime.h>
#include <hip/hip_bf16.h>
#include <math.h>

#define D   192
#define RPB 8        // rows per block

// acc[t][r] += dot(wrow[0..K), X[r][t][0..K)) ; X f32 in LDS
template<int K>
__device__ __forceinline__ void dense2(const float* __restrict__ wrow,
                                       const float* xbase, int ldr, int ldt,
                                       float (&acc)[2][RPB])
{
    const float4* w4 = (const float4*)wrow;
    for (int kk = 0; kk < K / 4; ++kk) {
        float4 w = w4[kk];
        #pragma unroll
        for (int t = 0; t < 2; ++t)
            #pragma unroll
            for (int r = 0; r < RPB; ++r) {
                const float4 xv = *(const float4*)(xbase + r * ldr + t * ldt + kk * 4);
                acc[t][r] += w.x * xv.x + w.y * xv.y + w.z * xv.z + w.w * xv.w;
            }
    }
}

// acc[r] += dot(wrow[0..K), X[r][0..K)) ; X f32 in LDS
template<int K>
__device__ __forceinline__ void dense1(const float* __restrict__ wrow,
                                       const float* xbase, int ldr,
                                       float (&acc)[RPB])
{
    const float4* w4 = (const float4*)wrow;
    for (int kk = 0; kk < K / 4; ++kk) {
        float4 w = w4[kk];
        #pragma unroll
        for (int r = 0; r < RPB; ++r) {
            const float4 xv = *(const float4*)(xbase + r * ldr + kk * 4);
            acc[r] += w.x * xv.x + w.y * xv.y + w.z * xv.z + w.w * xv.w;
        }
    }
}

// LDS arena: 18432 f32 = 72 KiB -> 2 blocks/CU. Region lifetimes (every
// transition crosses __syncthreads; audited stage-by-stage):
//   A [0    ,3072) : s_in   -> s_q   -> s_x2
//   B [3072 ,6144) : s_seq
//   C [6144 ,9216) : s_k    -> s_ctx -> s_z(1536)+s_ch(1536)
//   E [9216 ,12288): s_v    -> s_x1
//   F [12288,18432): s_h    -> s_fp
__global__ __launch_bounds__(192)
void fusion_head_kernel(
    const float* __restrict__ perc, const float* __restrict__ tech,
    const float* __restrict__ Wp,   const float* __restrict__ bp,
    const float* __restrict__ Wt,   const float* __restrict__ bt,
    const float* __restrict__ in_w, const float* __restrict__ in_b,
    const float* __restrict__ out_w,const float* __restrict__ out_b,
    const float* __restrict__ fw1,  const float* __restrict__ fb1,
    const float* __restrict__ fw2,  const float* __restrict__ fb2,
    const float* __restrict__ ln1g, const float* __restrict__ ln1b,
    const float* __restrict__ ln2g, const float* __restrict__ ln2b,
    const float* __restrict__ cw1,  const float* __restrict__ cb1,
    const float* __restrict__ cw2,  const float* __restrict__ cb2,
    const float* __restrict__ fpw,  const float* __restrict__ fpb,
    float* __restrict__ out, int B)
{
    __shared__ __align__(16) float smem[18432];
    __shared__ float s_att[RPB][3][2][2];        // attn probs [r][h][q][k]
    __shared__ float s_mu[RPB][2], s_rs[RPB][2], s_rn[RPB];

    float (*s_in )[2][D]   = (float(*)[2][D]  )(smem + 0);
    float (*s_seq)[2][D]   = (float(*)[2][D]  )(smem + 3072);
    float (*s_q  )[2][D]   = (float(*)[2][D]  )(smem + 0);          // reuses A
    float (*s_k  )[2][D]   = (float(*)[2][D]  )(smem + 6144);
    float (*s_v  )[2][D]   = (float(*)[2][D]  )(smem + 9216);
    float (*s_ctx)[2][D]   = (float(*)[2][D]  )(smem + 6144);       // reuses C
    float (*s_x1 )[2][D]   = (float(*)[2][D]  )(smem + 9216);       // reuses E
    float (*s_h  )[2][2*D] = (float(*)[2][2*D])(smem + 12288);
    float (*s_x2 )[2][D]   = (float(*)[2][D]  )(smem + 0);          // reuses A
    float (*s_z  )[D]      = (float(*)[D]     )(smem + 6144);       // C lo
    float (*s_ch )[D]      = (float(*)[D]     )(smem + 6144 + 1536);// C hi
    float (*s_fp )[128]    = (float(*)[128]   )(smem + 12288);      // reuses F

    const int  j    = threadIdx.x;                // 0..191 = output channel
    const long row0 = (long)blockIdx.x * RPB;

    // ---- load inputs (coalesced) ----
    #pragma unroll
    for (int r = 0; r < RPB; ++r) {
        s_in[r][0][j] = perc[(row0 + r) * D + j];
        s_in[r][1][j] = tech[(row0 + r) * D + j];
    }
    __syncthreads();

    // ---- proj_p / proj_t -> s_seq ----
    {
        float accP[RPB] = {}, accT[RPB] = {};
        dense1<D>(Wp + (size_t)j * D, &s_in[0][0][0], 2 * D, accP);
        dense1<D>(Wt + (size_t)j * D, &s_in[0][1][0], 2 * D, accT);
        float bbp = bp[j], bbt = bt[j];
        #pragma unroll
        for (int r = 0; r < RPB; ++r) {
            s_seq[r][0][j] = accP[r] + bbp;
            s_seq[r][1][j] = accT[r] + bbt;
        }
    }
    __syncthreads();   // s_in dead

    // ---- in-proj q,k,v ----
    {
        float accQ[2][RPB] = {}, accK[2][RPB] = {}, accV[2][RPB] = {};
        dense2<D>(in_w + (size_t)(0 * D + j) * D, &s_seq[0][0][0], 2 * D, D, accQ);
        dense2<D>(in_w + (size_t)(1 * D + j) * D, &s_seq[0][0][0], 2 * D, D, accK);
        dense2<D>(in_w + (size_t)(2 * D + j) * D, &s_seq[0][0][0], 2 * D, D, accV);
        float bq = in_b[0 * D + j];
        float bk = in_b[1 * D + j];
        float bv = in_b[2 * D + j];
        #pragma unroll
        for (int t = 0; t < 2; ++t)
            #pragma unroll
            for (int r = 0; r < RPB; ++r) {
                s_q[r][t][j] = accQ[t][r] + bq;
                s_k[r][t][j] = accK[t][r] + bk;
                s_v[r][t][j] = accV[t][r] + bv;
            }
    }
    __syncthreads();

    // ---- attention scores + softmax: one thread per (r, h) ----
    if (j < RPB * 3) {
        int r = j / 3, h = j - 3 * r;
        const float* q0 = &s_q[r][0][h * 64];
        const float* q1 = &s_q[r][1][h * 64];
        const float* k0 = &s_k[r][0][h * 64];
        const float* k1 = &s_k[r][1][h * 64];
        float s00 = 0.f, s01 = 0.f, s10 = 0.f, s11 = 0.f;
        for (int d = 0; d < 64; ++d) {
            float a0 = q0[d], a1 = q1[d], c0 = k0[d], c1 = k1[d];
            s00 += a0 * c0; s01 += a0 * c1;
            s10 += a1 * c0; s11 += a1 * c1;
        }
        const float scl = 0.125f;  // 1/sqrt(64)
        s00 *= scl; s01 *= scl; s10 *= scl; s11 *= scl;
        float m0 = fmaxf(s00, s01);
        float e00 = expf(s00 - m0), e01 = expf(s01 - m0);
        float i0 = 1.f / (e00 + e01);
        s_att[r][h][0][0] = e00 * i0;
        s_att[r][h][0][1] = e01 * i0;
        float m1 = fmaxf(s10, s11);
        float e10 = expf(s10 - m1), e11 = expf(s11 - m1);
        float i1 = 1.f / (e10 + e11);
        s_att[r][h][1][0] = e10 * i1;
        s_att[r][h][1][1] = e11 * i1;
    }
    __syncthreads();

    // ---- ctx = attn @ v -> C (s_k dead) ----
    {
        int h = j >> 6;
        #pragma unroll
        for (int r = 0; r < RPB; ++r) {
            float v0 = s_v[r][0][j], v1 = s_v[r][1][j];
            s_ctx[r][0][j] = s_att[r][h][0][0] * v0 + s_att[r][h][0][1] * v1;
            s_ctx[r][1][j] = s_att[r][h][1][0] * v0 + s_att[r][h][1][1] * v1;
        }
    }
    __syncthreads();   // s_v dead

    // ---- out-proj + residual -> s_x1 (E) ----
    {
        float acc[2][RPB] = {};
        dense2<D>(out_w + (size_t)j * D, &s_ctx[0][0][0], 2 * D, D, acc);
        float bb = out_b[j];
        #pragma unroll
        for (int t = 0; t < 2; ++t)
            #pragma unroll
            for (int r = 0; r < RPB; ++r)
                s_x1[r][t][j] = s_seq[r][t][j] + acc[t][r] + bb;
    }
    __syncthreads();   // s_seq, s_ctx dead

    // ---- LN1 ----
    if (j < RPB * 2) {
        int r = j >> 1, t = j & 1;
        float s = 0.f, s2 = 0.f;
        for (int c = 0; c < D; ++c) { float y = s_x1[r][t][c]; s += y; s2 += y * y; }
        float mu  = s * (1.f / D);
        float var = s2 * (1.f / D) - mu * mu;
        s_mu[r][t] = mu;
        s_rs[r][t] = rsqrtf(var + 1e-5f);
    }
    __syncthreads();
    {
        float g = ln1g[j], b = ln1b[j];
        #pragma unroll
        for (int r = 0; r < RPB; ++r)
            #pragma unroll
            for (int t = 0; t < 2; ++t)
                s_x1[r][t][j] = (s_x1[r][t][j] - s_mu[r][t]) * s_rs[r][t] * g + b;
    }
    __syncthreads();

    // ---- FFN1 (384 outputs, relu) -> s_h ----
    {
        float acc[2][RPB] = {};
        dense2<D>(fw1 + (size_t)j * D, &s_x1[0][0][0], 2 * D, D, acc);
        float bb = fb1[j];
        #pragma unroll
        for (int t = 0; t < 2; ++t)
            #pragma unroll
            for (int r = 0; r < RPB; ++r)
                s_h[r][t][j] = fmaxf(acc[t][r] + bb, 0.f);
    }
    {
        float acc[2][RPB] = {};
        dense2<D>(fw1 + (size_t)(D + j) * D, &s_x1[0][0][0], 2 * D, D, acc);
        float bb = fb1[D + j];
        #pragma unroll
        for (int t = 0; t < 2; ++t)
            #pragma unroll
            for (int r = 0; r < RPB; ++r)
                s_h[r][t][D + j] = fmaxf(acc[t][r] + bb, 0.f);
    }
    __syncthreads();

    // ---- FFN2 (K=384) + residual -> s_x2 (A) ----
    {
        float acc[2][RPB] = {};
        dense2<2 * D>(fw2 + (size_t)j * (2 * D), &s_h[0][0][0], 2 * (2 * D), 2 * D, acc);
        float bb = fb2[j];
        #pragma unroll
        for (int t = 0; t < 2; ++t)
            #pragma unroll
            for (int r = 0; r < RPB; ++r)
                s_x2[r][t][j] = s_x1[r][t][j] + acc[t][r] + bb;
    }
    __syncthreads();   // s_x1, s_h dead

    // ---- LN2 ----
    if (j < RPB * 2) {
        int r = j >> 1, t = j & 1;
        float s = 0.f, s2 = 0.f;
        for (int c = 0; c < D; ++c) { float y = s_x2[r][t][c]; s += y; s2 += y * y; }
        float mu  = s * (1.f / D);
        float var = s2 * (1.f / D) - mu * mu;
        s_mu[r][t] = mu;
        s_rs[r][t] = rsqrtf(var + 1e-5f);
    }
    __syncthreads();
    {
        float g = ln2g[j], b = ln2b[j];
        #pragma unroll
        for (int r = 0; r < RPB; ++r) {
            float a0 = (s_x2[r][0][j] - s_mu[r][0]) * s_rs[r][0] * g + b;
            float a1 = (s_x2[r][1][j] - s_mu[r][1]) * s_rs[r][1] * g + b;
            s_z[r][j] = 0.5f * (a0 + a1);
        }
    }
    __syncthreads();

    // ---- cls hidden -> s_ch ; fingerprint -> s_fp ----
    {
        float acc[RPB] = {};
        dense1<D>(cw1 + (size_t)j * D, &s_z[0][0], D, acc);
        float bb = cb1[j];
        #pragma unroll
        for (int r = 0; r < RPB; ++r) s_ch[r][j] = fmaxf(acc[r] + bb, 0.f);
    }
    if (j < 128) {
        float acc[RPB] = {};
        dense1<D>(fpw + (size_t)j * D, &s_z[0][0], D, acc);
        float bb = fpb[j];
        #pragma unroll
        for (int r = 0; r < RPB; ++r) s_fp[r][j] = acc[r] + bb;
    }
    __syncthreads();

    // ---- logits + sigmoid -> out[c*B + row]  (f32 stores!) ----
    if (j < RPB * 3) {
        int r = j / 3, c = j - 3 * r;
        float a = 0.f;
        const float* w = cw2 + (size_t)c * D;
        for (int k = 0; k < D; ++k) a += w[k] * s_ch[r][k];
        a += cb2[c];
        out[(size_t)c * B + (size_t)(row0 + r)] = 1.f / (1.f + expf(-a));
    }
    // ---- fingerprint norm ----
    if (j < RPB) {
        float s2 = 0.f;
        for (int k = 0; k < 128; ++k) { float v = s_fp[j][k]; s2 += v * v; }
        s_rn[j] = 1.f / fmaxf(sqrtf(s2), 1e-12f);
    }
    __syncthreads();

    // ---- normalized fingerprint -> out[3B + row*128 + j]  (f32 stores!) ----
    if (j < 128) {
        #pragma unroll
        for (int r = 0; r < RPB; ++r)
            out[(size_t)3 * B + (size_t)(row0 + r) * 128 + j] = s_fp[r][j] * s_rn[r];
    }
}

extern "C" void kernel_launch(void* const* d_in, const int* in_sizes, int n_in,
                              void* d_out, int out_size, void* d_ws, size_t ws_size,
                              hipStream_t stream) {
    const float* perc = (const float*)d_in[0];
    const float* tech = (const float*)d_in[1];
    const float* Wp   = (const float*)d_in[2];
    const float* bp   = (const float*)d_in[3];
    const float* Wt   = (const float*)d_in[4];
    const float* bt   = (const float*)d_in[5];
    const float* in_w = (const float*)d_in[6];
    const float* in_b = (const float*)d_in[7];
    const float* ow   = (const float*)d_in[8];
    const float* ob   = (const float*)d_in[9];
    const float* fw1  = (const float*)d_in[10];
    const float* fb1  = (const float*)d_in[11];
    const float* fw2  = (const float*)d_in[12];
    const float* fb2  = (const float*)d_in[13];
    const float* ln1g = (const float*)d_in[14];
    const float* ln1b = (const float*)d_in[15];
    const float* ln2g = (const float*)d_in[16];
    const float* ln2b = (const float*)d_in[17];
    const float* cw1  = (const float*)d_in[18];
    const float* cb1  = (const float*)d_in[19];
    const float* cw2  = (const float*)d_in[20];
    const float* cb2  = (const float*)d_in[21];
    const float* fpw  = (const float*)d_in[22];
    const float* fpb  = (const float*)d_in[23];

    int B = in_sizes[0] / D;
    dim3 grid(B / RPB), block(192);
    hipLaunchKernelGGL(fusion_head_kernel, grid, block, 0, stream,
                       perc, tech, Wp, bp, Wt, bt, in_w, in_b, ow, ob,
                       fw1, fb1, fw2, fb2, ln1g, ln1b, ln2g, ln2b,
                       cw1, cb1, cw2, cb2, fpw, fpb,
                       (float*)d_out, B);
}

// Round 6
// 629.391 us; speedup vs baseline: 4.9230x; 4.9230x over previous
//
#include <hip/hip_runtime.h>
#include <hip/hip_bf16.h>
#include <math.h>

#define D 192
#define RPB 16                       // rows per block -> M = 32 tokens
typedef unsigned short u16;
typedef __attribute__((ext_vector_type(8))) short short8;   // 8 bf16 (4 VGPRs)
typedef __attribute__((ext_vector_type(4))) float float4v;  // MFMA C/D

__device__ __forceinline__ float b2f(u16 u){ union{unsigned i; float f;}c; c.i=(unsigned)u<<16; return c.f; }
__device__ __forceinline__ u16  f2b(float f){
    union{float f; unsigned i;}c; c.f=f;
    unsigned r = c.i + 0x7FFFu + ((c.i>>16)&1u);   // RTNE
    return (u16)(r>>16);
}

// ---- bf16 weight arena in d_ws (row-major [N][K], element offsets) ----
#define WP_OFF   0
#define WT_OFF   36864
#define INW_OFF  73728
#define OUTW_OFF 184320
#define FW1_OFF  221184
#define FW2_OFF  294912
#define CW1_OFF  368640
#define FPW_OFF  405504
#define W_TOTAL  430080            // elements; 860160 bytes

__global__ __launch_bounds__(256)
void cvt_weights(const float* __restrict__ Wp, const float* __restrict__ Wt,
                 const float* __restrict__ in_w, const float* __restrict__ out_w,
                 const float* __restrict__ fw1, const float* __restrict__ fw2,
                 const float* __restrict__ cw1, const float* __restrict__ fpw,
                 u16* __restrict__ ws)
{
    int idx = blockIdx.x * 256 + threadIdx.x;
    if (idx >= W_TOTAL) return;
    const float* src; int off;
    if      (idx < WT_OFF)   { src = Wp;   off = WP_OFF; }
    else if (idx < INW_OFF)  { src = Wt;   off = WT_OFF; }
    else if (idx < OUTW_OFF) { src = in_w; off = INW_OFF; }
    else if (idx < FW1_OFF)  { src = out_w;off = OUTW_OFF; }
    else if (idx < FW2_OFF)  { src = fw1;  off = FW1_OFF; }
    else if (idx < CW1_OFF)  { src = fw2;  off = FW2_OFF; }
    else if (idx < FPW_OFF)  { src = cw1;  off = CW1_OFF; }
    else                     { src = fpw;  off = FPW_OFF; }
    ws[idx] = f2b(src[idx - off]);
}

// A-frag: lane holds A[m = mt*16 + lane16][k = quad*8 + j] for k-step ks (k += 32*ks)
template<int KT, int MT>
__device__ __forceinline__ void load_afrags(short8 (&A)[MT][KT], const u16* base,
                                            int stride, int lane16, int quad)
{
    #pragma unroll
    for (int mt = 0; mt < MT; ++mt)
        #pragma unroll
        for (int ks = 0; ks < KT; ++ks)
            A[mt][ks] = *(const short8*)(base + (mt*16 + lane16)*stride + ks*32 + quad*8);
}

// C tile (M=MT*16, N=NTW*4 waves*16): B streamed from global bf16 [N][K] rows.
// C/D layout: row = quad*4 + reg, col = lane16 (m89-verified).
template<int KT, int MT, int NTW>
__device__ __forceinline__ void run_gemm(const short8 (&A)[MT][KT],
    const u16* __restrict__ wsb, const float* __restrict__ bias,
    u16* dst, float* dstf, int dstride,
    const u16* resid, int rstride, bool relu, int rmul, int roff,
    int wave, int lane16, int quad)
{
    const int K = KT * 32;
    #pragma unroll
    for (int i = 0; i < NTW; ++i) {
        int nt = wave + 4*i, n0 = nt*16;
        float4v c[MT];
        #pragma unroll
        for (int mt = 0; mt < MT; ++mt) c[mt] = (float4v){0.f,0.f,0.f,0.f};
        #pragma unroll
        for (int ks = 0; ks < KT; ++ks) {
            short8 b = *(const short8*)(wsb + (size_t)(n0 + lane16)*K + ks*32 + quad*8);
            #pragma unroll
            for (int mt = 0; mt < MT; ++mt)
                c[mt] = __builtin_amdgcn_mfma_f32_16x16x32_bf16(A[mt][ks], b, c[mt], 0,0,0);
        }
        float bv = bias[n0 + lane16];
        #pragma unroll
        for (int mt = 0; mt < MT; ++mt)
            #pragma unroll
            for (int ii = 0; ii < 4; ++ii) {
                int dr = (mt*16 + quad*4 + ii)*rmul + roff;
                float v = c[mt][ii] + bv;
                if (resid) v += b2f(resid[dr*rstride + n0 + lane16]);
                if (relu)  v = fmaxf(v, 0.f);
                if (dst) dst [dr*dstride + n0 + lane16] = f2b(v);
                else     dstf[dr*dstride + n0 + lane16] = v;
            }
    }
}

// ---- LDS arena (u16 elements), stride 200 for K=192 rows, 392 for h ----
#define S1 200
#define SH 392
#define A_INP 0          // 16x200  -> later ctx (32x200 @0) -> later z(@0)+ch(@3200)
#define A_INT 3200
#define A_SEQ 6400       // 32x200  -> later x2
#define A_Q   12800      // 32x200  -> later x1
#define A_K   19200      // 32x200  -> later h (32x392 spans 19200..31744) -> fpf f32
#define A_V   25600
#define A_CTX 0
#define A_X1  12800
#define A_H   19200
#define A_X2  6400
#define A_Z   0
#define A_CH  3200
#define ARENA_U16 32000

__global__ __launch_bounds__(256)
void fusion_mfma_kernel(
    const float* __restrict__ perc, const float* __restrict__ tech,
    const float* __restrict__ bp,   const float* __restrict__ bt,
    const float* __restrict__ in_b, const float* __restrict__ out_b,
    const float* __restrict__ fb1,  const float* __restrict__ fb2,
    const float* __restrict__ ln1g, const float* __restrict__ ln1b,
    const float* __restrict__ ln2g, const float* __restrict__ ln2b,
    const float* __restrict__ cb1,  const float* __restrict__ cw2,
    const float* __restrict__ cb2,  const float* __restrict__ fpb,
    const u16*   __restrict__ ws,
    float* __restrict__ out, int B)
{
    __shared__ __align__(16) u16 arena[ARENA_U16];
    __shared__ float satt[16][3][2][2];   // raw scores then probs
    __shared__ float sred[32][8][2];      // LN partials
    __shared__ float smu[32], srs[32], srn[16];

    const int tid = threadIdx.x;
    const int wave = tid >> 6, lane = tid & 63;
    const int lane16 = lane & 15, quad = lane >> 4;
    const int row0 = blockIdx.x * RPB;
    float* fpf = (float*)(arena + A_H);   // 16x128 f32 (over dead h)

    // ---- stage inputs -> bf16 LDS (inP, inT) ----
    #pragma unroll
    for (int it = 0; it < 12; ++it) {
        int idx = it*256 + tid;           // 12*256 = 3072 = 16*192
        int r = idx / 192, c = idx - r*192;
        arena[A_INP + r*S1 + c] = f2b(perc[(size_t)(row0 + r)*D + c]);
        arena[A_INT + r*S1 + c] = f2b(tech[(size_t)(row0 + r)*D + c]);
    }
    __syncthreads();

    // ---- proj_p / proj_t -> seq (tokens interleaved: row 2r / 2r+1) ----
    {
        short8 A1[1][6];
        load_afrags<6,1>(A1, arena + A_INP, S1, lane16, quad);
        run_gemm<6,1,3>(A1, ws + WP_OFF, bp, arena + A_SEQ, nullptr, S1,
                        nullptr, 0, false, 2, 0, wave, lane16, quad);
        load_afrags<6,1>(A1, arena + A_INT, S1, lane16, quad);
        run_gemm<6,1,3>(A1, ws + WT_OFF, bt, arena + A_SEQ, nullptr, S1,
                        nullptr, 0, false, 2, 1, wave, lane16, quad);
    }
    __syncthreads();

    // ---- qkv (A = seq, M=32) ----
    {
        short8 A2[2][6];
        load_afrags<6,2>(A2, arena + A_SEQ, S1, lane16, quad);
        run_gemm<6,2,3>(A2, ws + INW_OFF,           in_b,       arena + A_Q, nullptr, S1,
                        nullptr, 0, false, 1, 0, wave, lane16, quad);
        run_gemm<6,2,3>(A2, ws + INW_OFF + 192*192, in_b + 192, arena + A_K, nullptr, S1,
                        nullptr, 0, false, 1, 0, wave, lane16, quad);
        run_gemm<6,2,3>(A2, ws + INW_OFF + 384*192, in_b + 384, arena + A_V, nullptr, S1,
                        nullptr, 0, false, 1, 0, wave, lane16, quad);
    }
    __syncthreads();

    // ---- attention scores (one thread per r,h,qt,kt) ----
    if (tid < 192) {
        int r = tid / 12, rem = tid - r*12;
        int h = rem >> 2, qt = (rem >> 1) & 1, kt = rem & 1;
        const u16* qp = arena + A_Q + (2*r + qt)*S1 + h*64;
        const u16* kp = arena + A_K + (2*r + kt)*S1 + h*64;
        float s = 0.f;
        for (int d = 0; d < 64; ++d) s += b2f(qp[d]) * b2f(kp[d]);
        satt[r][h][qt][kt] = s * 0.125f;
    }
    __syncthreads();
    if (tid < 96) {
        int r = tid / 6, rem = tid - r*6;
        int h = rem >> 1, qt = rem & 1;
        float s0 = satt[r][h][qt][0], s1 = satt[r][h][qt][1];
        float m = fmaxf(s0, s1);
        float e0 = expf(s0 - m), e1 = expf(s1 - m);
        float inv = 1.f / (e0 + e1);
        satt[r][h][qt][0] = e0 * inv;
        satt[r][h][qt][1] = e1 * inv;
    }
    __syncthreads();

    // ---- ctx = attn @ v -> A_CTX (over dead inP/inT) ----
    #pragma unroll
    for (int it = 0; it < 24; ++it) {
        int idx = it*256 + tid;          // 32*192 = 6144
        int tok = idx / 192, ch = idx - tok*192;
        int r = tok >> 1, qt = tok & 1, h = ch >> 6;
        float v0 = b2f(arena[A_V + (2*r    )*S1 + ch]);
        float v1 = b2f(arena[A_V + (2*r + 1)*S1 + ch]);
        arena[A_CTX + tok*S1 + ch] = f2b(satt[r][h][qt][0]*v0 + satt[r][h][qt][1]*v1);
    }
    __syncthreads();

    // ---- out-proj + residual(seq) -> x1 (pre-LN1) ----
    {
        short8 A2[2][6];
        load_afrags<6,2>(A2, arena + A_CTX, S1, lane16, quad);
        run_gemm<6,2,3>(A2, ws + OUTW_OFF, out_b, arena + A_X1, nullptr, S1,
                        arena + A_SEQ, S1, false, 1, 0, wave, lane16, quad);
    }
    __syncthreads();

    // ---- LN1 (in-place on x1) ----
    {
        int tok = tid >> 3, sub = tid & 7;
        const u16* xr = arena + A_X1 + tok*S1 + sub*24;
        float s = 0.f, s2 = 0.f;
        for (int c = 0; c < 24; ++c) { float y = b2f(xr[c]); s += y; s2 += y*y; }
        sred[tok][sub][0] = s; sred[tok][sub][1] = s2;
    }
    __syncthreads();
    if (tid < 32) {
        float s = 0.f, s2 = 0.f;
        for (int k = 0; k < 8; ++k) { s += sred[tid][k][0]; s2 += sred[tid][k][1]; }
        float mu = s * (1.f/192.f);
        float var = s2 * (1.f/192.f) - mu*mu;
        smu[tid] = mu; srs[tid] = rsqrtf(var + 1e-5f);
    }
    __syncthreads();
    #pragma unroll
    for (int it = 0; it < 24; ++it) {
        int idx = it*256 + tid;
        int tok = idx / 192, ch = idx - tok*192;
        u16* p = arena + A_X1 + tok*S1 + ch;
        *p = f2b((b2f(*p) - smu[tok]) * srs[tok] * ln1g[ch] + ln1b[ch]);
    }
    __syncthreads();

    // ---- FFN1 (relu) -> h ----
    {
        short8 A2[2][6];
        load_afrags<6,2>(A2, arena + A_X1, S1, lane16, quad);
        run_gemm<6,2,6>(A2, ws + FW1_OFF, fb1, arena + A_H, nullptr, SH,
                        nullptr, 0, true, 1, 0, wave, lane16, quad);
    }
    __syncthreads();

    // ---- FFN2 (K=384, chunked) + residual(x1) -> x2 (pre-LN2) ----
    {
        float4v c[3][2];
        #pragma unroll
        for (int i = 0; i < 3; ++i) { c[i][0] = (float4v){0,0,0,0}; c[i][1] = (float4v){0,0,0,0}; }
        #pragma unroll
        for (int kc = 0; kc < 2; ++kc) {
            short8 Af[2][6];
            load_afrags<6,2>(Af, arena + A_H + kc*192, SH, lane16, quad);
            #pragma unroll
            for (int i = 0; i < 3; ++i) {
                int n0 = (wave + 4*i)*16;
                #pragma unroll
                for (int ks = 0; ks < 6; ++ks) {
                    short8 b = *(const short8*)(ws + FW2_OFF + (size_t)(n0+lane16)*384 + kc*192 + ks*32 + quad*8);
                    c[i][0] = __builtin_amdgcn_mfma_f32_16x16x32_bf16(Af[0][ks], b, c[i][0], 0,0,0);
                    c[i][1] = __builtin_amdgcn_mfma_f32_16x16x32_bf16(Af[1][ks], b, c[i][1], 0,0,0);
                }
            }
        }
        #pragma unroll
        for (int i = 0; i < 3; ++i) {
            int n0 = (wave + 4*i)*16;
            float bv = fb2[n0 + lane16];
            #pragma unroll
            for (int mt = 0; mt < 2; ++mt)
                #pragma unroll
                for (int ii = 0; ii < 4; ++ii) {
                    int dr = mt*16 + quad*4 + ii;
                    float v = c[i][mt][ii] + bv + b2f(arena[A_X1 + dr*S1 + n0 + lane16]);
                    arena[A_X2 + dr*S1 + n0 + lane16] = f2b(v);
                }
        }
    }
    __syncthreads();

    // ---- LN2 + token-mean -> z ----
    {
        int tok = tid >> 3, sub = tid & 7;
        const u16* xr = arena + A_X2 + tok*S1 + sub*24;
        float s = 0.f, s2 = 0.f;
        for (int c = 0; c < 24; ++c) { float y = b2f(xr[c]); s += y; s2 += y*y; }
        sred[tok][sub][0] = s; sred[tok][sub][1] = s2;
    }
    __syncthreads();
    if (tid < 32) {
        float s = 0.f, s2 = 0.f;
        for (int k = 0; k < 8; ++k) { s += sred[tid][k][0]; s2 += sred[tid][k][1]; }
        float mu = s * (1.f/192.f);
        float var = s2 * (1.f/192.f) - mu*mu;
        smu[tid] = mu; srs[tid] = rsqrtf(var + 1e-5f);
    }
    __syncthreads();
    #pragma unroll
    for (int it = 0; it < 12; ++it) {
        int idx = it*256 + tid;          // 16*192 = 3072
        int r = idx / 192, ch = idx - r*192;
        float g = ln2g[ch], bb = ln2b[ch];
        float n0 = (b2f(arena[A_X2 + (2*r    )*S1 + ch]) - smu[2*r    ]) * srs[2*r    ] * g + bb;
        float n1 = (b2f(arena[A_X2 + (2*r + 1)*S1 + ch]) - smu[2*r + 1]) * srs[2*r + 1] * g + bb;
        arena[A_Z + r*S1 + ch] = f2b(0.5f * (n0 + n1));
    }
    __syncthreads();

    // ---- heads: cls1 (relu -> ch), fingerprint (f32 -> fpf) ----
    {
        short8 A1[1][6];
        load_afrags<6,1>(A1, arena + A_Z, S1, lane16, quad);
        run_gemm<6,1,3>(A1, ws + CW1_OFF, cb1, arena + A_CH, nullptr, S1,
                        nullptr, 0, true, 1, 0, wave, lane16, quad);
        run_gemm<6,1,2>(A1, ws + FPW_OFF, fpb, nullptr, fpf, 128,
                        nullptr, 0, false, 1, 0, wave, lane16, quad);
    }
    __syncthreads();

    // ---- cls2 + sigmoid ----
    if (tid < 48) {
        int r = tid / 3, cc = tid - r*3;
        float a = cb2[cc];
        const float* w = cw2 + (size_t)cc * D;
        const u16* hr = arena + A_CH + r*S1;
        for (int k = 0; k < D; ++k) a += w[k] * b2f(hr[k]);
        out[(size_t)cc * B + (size_t)(row0 + r)] = 1.f / (1.f + expf(-a));
    }
    // ---- fingerprint norm ----
    if (tid < 16) {
        float s2 = 0.f;
        for (int k = 0; k < 128; ++k) { float v = fpf[tid*128 + k]; s2 += v*v; }
        srn[tid] = 1.f / fmaxf(sqrtf(s2), 1e-12f);
    }
    __syncthreads();
    #pragma unroll
    for (int it = 0; it < 8; ++it) {
        int idx = it*256 + tid;          // 16*128 = 2048
        int r = idx >> 7, c = idx & 127;
        out[(size_t)3*B + (size_t)(row0 + r)*128 + c] = fpf[r*128 + c] * srn[r];
    }
}

extern "C" void kernel_launch(void* const* d_in, const int* in_sizes, int n_in,
                              void* d_out, int out_size, void* d_ws, size_t ws_size,
                              hipStream_t stream) {
    if (ws_size < (size_t)W_TOTAL * 2) return;   // visible failure -> ws too small

    const float* perc = (const float*)d_in[0];
    const float* tech = (const float*)d_in[1];
    const float* Wp   = (const float*)d_in[2];
    const float* bp   = (const float*)d_in[3];
    const float* Wt   = (const float*)d_in[4];
    const float* bt   = (const float*)d_in[5];
    const float* in_w = (const float*)d_in[6];
    const float* in_b = (const float*)d_in[7];
    const float* ow   = (const float*)d_in[8];
    const float* ob   = (const float*)d_in[9];
    const float* fw1  = (const float*)d_in[10];
    const float* fb1  = (const float*)d_in[11];
    const float* fw2  = (const float*)d_in[12];
    const float* fb2  = (const float*)d_in[13];
    const float* ln1g = (const float*)d_in[14];
    const float* ln1b = (const float*)d_in[15];
    const float* ln2g = (const float*)d_in[16];
    const float* ln2b = (const float*)d_in[17];
    const float* cw1  = (const float*)d_in[18];
    const float* cb1  = (const float*)d_in[19];
    const float* cw2  = (const float*)d_in[20];
    const float* cb2  = (const float*)d_in[21];
    const float* fpw  = (const float*)d_in[22];
    const float* fpb  = (const float*)d_in[23];

    u16* ws = (u16*)d_ws;
    int B = in_sizes[0] / D;

    hipLaunchKernelGGL(cvt_weights, dim3((W_TOTAL + 255)/256), dim3(256), 0, stream,
                       Wp, Wt, in_w, ow, fw1, fw2, cw1, fpw, ws);

    hipLaunchKernelGGL(fusion_mfma_kernel, dim3(B / RPB), dim3(256), 0, stream,
                       perc, tech, bp, bt, in_b, ob, fb1, fb2,
                       ln1g, ln1b, ln2g, ln2b, cb1, cw2, cb2, fpb,
                       ws, (float*)d_out, B);
}